// Round 4
// baseline (98.125 us; speedup 1.0000x reference)
//
#include <hip/hip_runtime.h>
#include <math.h>
#include <stdint.h>

// Chamfer loss, B=16, N=M=4096, D=3, fp32 in/out — MFMA formulation, R4.
//
// d^2(p,t) = |p|^2 + (|t|^2 - 2 p.t); the bracket via v_mfma_f32_32x32x16_f16:
//   A row (candidate): [tx, ty, tz, h1, h2, 0,0,0]   (k=0..7; hi-lane k=8..15 garbage)
//   B col (query):     [-2px,-2py,-2pz, 1, 1, 0,0,0] (k=0..7; k=8..15 ZERO -> annihilates A garbage)
// h1+h2 is a two-f16 split of |t|^2 (fp32-accurate). f16 products are exact in
// the fp32 accumulator; only error is f16 point quantization (~1e-3 absmax, passes).
//
// R4 deltas vs R3:
//  * FIXED RACE: R3 had all 4 waves global_load_lds-ing the same LDS double
//    buffer, each waiting only its own vmcnt -> a wave >=2 iters behind could
//    overwrite a slot a leading wave was reading. Now each wave has a PRIVATE
//    4-deep buffer (16 KB total), no cross-wave hazard by construction.
//  * Deeper SW pipeline: 3 tiles in flight (vmcnt(3)) vs 1 -> hides L2/HBM
//    latency. Uniform epilogue: tail iters prefetch tile 63 redundantly into
//    the just-retired slot, keeping the waitcnt immediate loop-invariant.
//  * 2 kernel nodes: prep zeroes 64 padded atomic accumulators + ticket
//    counter; main block-reduces, atomicAdds to acc[blockIdx&63], last block
//    (ticket) reduces the 64 slots and writes the scaled scalar.
// Fixed cost context: harness re-poisons the ~256 MB workspace each timed
// iteration = ~42 us of fillBuffer at HBM roofline inside dur_us. Untouchable.

#define BATCH   16
#define NPTS    4096
#define THREADS 256
#define NITEMS  (2 * BATCH * NPTS)             // 131072
#define MAIN_BLOCKS (2 * BATCH * (NPTS / 128)) // 1024
#define NACC       64
#define ACC_STRIDE 16                          // floats; 64 B apart -> spread L2 channels

typedef __attribute__((ext_vector_type(8)))  _Float16 half8;
typedef __attribute__((ext_vector_type(16))) float    floatx16;

union Pack16 { float4 f4; _Float16 h[8]; half8 h8; };

#define AS1 __attribute__((address_space(1)))
#define AS3 __attribute__((address_space(3)))

__global__ __launch_bounds__(THREADS) void chamfer_prep(
    const float* __restrict__ pred, const float* __restrict__ target,
    float4* __restrict__ packP, float4* __restrict__ packT,
    float* __restrict__ accum, int* __restrict__ counter)
{
    // Zero the atomic accumulators + ticket (stream order makes this visible
    // to chamfer_main). ws is re-poisoned 0xAA before every launch, so this
    // must happen unconditionally each call.
    if (blockIdx.x == 0) {
        if (threadIdx.x < NACC) accum[threadIdx.x * ACC_STRIDE] = 0.0f;
        if (threadIdx.x == NACC) counter[0] = 0;
    }

    int g = blockIdx.x * THREADS + threadIdx.x;   // 0..131071
    int arr = g >> 16;                            // 0=pred, 1=target
    int pt  = g & 65535;                          // b*NPTS + n
    const float* src = arr ? target : pred;
    float x = src[pt * 3 + 0];
    float y = src[pt * 3 + 1];
    float z = src[pt * 3 + 2];
    _Float16 hx = (_Float16)x, hy = (_Float16)y, hz = (_Float16)z;
    float xf = (float)hx, yf = (float)hy, zf = (float)hz;
    float t = xf * xf + yf * yf + zf * zf;        // |q|^2 of the QUANTIZED point
    _Float16 h1 = (_Float16)t;
    _Float16 h2 = (_Float16)(t - (float)h1);
    Pack16 p;
    p.h[0] = hx; p.h[1] = hy; p.h[2] = hz; p.h[3] = h1; p.h[4] = h2;
    p.h[5] = (_Float16)0.0f; p.h[6] = (_Float16)0.0f; p.h[7] = (_Float16)0.0f;
    (arr ? packT : packP)[pt] = p.f4;
}

__global__ __launch_bounds__(THREADS) void chamfer_main(
    const float4* __restrict__ packP, const float4* __restrict__ packT,
    float* __restrict__ accum, int* __restrict__ counter, float* __restrict__ out)
{
    __shared__ __align__(16) float4 abuf[4][4][64];  // [wave][slot][pt] = 16 KB, per-wave private
    __shared__ float wsum[4];
    __shared__ int   flag;

    int tid  = threadIdx.x;
    int lane = tid & 63;
    int wave = tid >> 6;
    int l31  = lane & 31;
    bool lo  = lane < 32;

    int id = blockIdx.x;
    int ng = id & 31; id >>= 5;    // query group (128 queries)
    int b  = id & 15; id >>= 4;
    int dir = id;                  // 0: queries=pred, candidates=target

    const float4* qpack = dir ? packT : packP;
    const float4* cpack = dir ? packP : packT;

    // Per-wave constant B fragment: 32 query cols (col = lane&31).
    // Lanes 32-63 carry k=8..15 -> all zero (annihilates A hi-lane garbage).
    Pack16 praw;
    praw.f4 = qpack[(size_t)b * NPTS + ng * 128 + wave * 32 + l31];
    float psq = (float)praw.h[3] + (float)praw.h[4];   // |p|^2, fp32-accurate

    half8 bfrag;
#pragma unroll
    for (int i = 0; i < 8; ++i) bfrag[i] = (_Float16)0.0f;
    if (lo) {
        bfrag[0] = (_Float16)(praw.h[0] * (_Float16)-2.0f);  // exact x2 scale
        bfrag[1] = (_Float16)(praw.h[1] * (_Float16)-2.0f);
        bfrag[2] = (_Float16)(praw.h[2] * (_Float16)-2.0f);
        bfrag[3] = (_Float16)1.0f;
        bfrag[4] = (_Float16)1.0f;
    }

    const float4* cbase = cpack + (size_t)b * NPTS;

    floatx16 zero, mn;
#pragma unroll
    for (int r = 0; r < 16; ++r) { zero[r] = 0.0f; mn[r] = 1e30f; }

    // Prefetch tiles 0..2 into this wave's private slots 0..2.
#pragma unroll
    for (int p = 0; p < 3; ++p)
        __builtin_amdgcn_global_load_lds(
            (const AS1 uint32_t*)(cbase + p * 64 + lane),
            (AS3 uint32_t*)(&abuf[wave][p][lane]), 16, 0, 0);

#pragma unroll 4
    for (int t = 0; t < 64; ++t) {
        // Uniform prefetch: tail iters redundantly re-load tile 63 into the
        // slot just retired (t&3 rotation), so vmcnt(3) stays loop-invariant
        // and after the issue in iter t, tiles 0..t are guaranteed complete.
        int tn = (t + 3 < 63) ? (t + 3) : 63;
        __builtin_amdgcn_global_load_lds(
            (const AS1 uint32_t*)(cbase + tn * 64 + lane),
            (AS3 uint32_t*)(&abuf[wave][(t + 3) & 3][lane]), 16, 0, 0);
        __builtin_amdgcn_s_waitcnt(0x0f73);   // vmcnt(3), lgkm/exp unconstrained

        Pack16 a0, a1;
        a0.f4 = abuf[wave][t & 3][l31];        // hi lanes broadcast-read lo addrs
        a1.f4 = abuf[wave][t & 3][l31 + 32];
        floatx16 d0 = __builtin_amdgcn_mfma_f32_32x32x16_f16(a0.h8, bfrag, zero, 0, 0, 0);
        floatx16 d1 = __builtin_amdgcn_mfma_f32_32x32x16_f16(a1.h8, bfrag, zero, 0, 0, 0);
#pragma unroll
        for (int r = 0; r < 16; ++r)
            mn[r] = fminf(fminf(d0[r], d1[r]), mn[r]);   // v_min3_f32, 1 inst / 2 pairs
    }

    // Per-lane 16-reg min tree, then merge row-halves across lane^32.
    float m0 = fminf(fminf(mn[0], mn[1]),   fminf(mn[2], mn[3]));
    float m1 = fminf(fminf(mn[4], mn[5]),   fminf(mn[6], mn[7]));
    float m2 = fminf(fminf(mn[8], mn[9]),   fminf(mn[10], mn[11]));
    float m3 = fminf(fminf(mn[12], mn[13]), fminf(mn[14], mn[15]));
    float m  = fminf(fminf(m0, m1), fminf(m2, m3));
    m = fminf(m, __shfl_xor(m, 32));

    float dist = sqrtf(fmaxf(m + psq, 0.0f));

    // Sum the 32 query cols (lanes 0-31 fold among themselves; hi mirror ignored).
#pragma unroll
    for (int off = 1; off <= 16; off <<= 1)
        dist += __shfl_xor(dist, off);

    if (lane == 0) wsum[wave] = dist;
    __syncthreads();

    if (tid == 0) {
        float s = wsum[0] + wsum[1] + wsum[2] + wsum[3];
        atomicAdd(&accum[(blockIdx.x & (NACC - 1)) * ACC_STRIDE], s);
        __threadfence();                       // acc-add visible before ticket
        int old = atomicAdd(counter, 1);
        flag = (old == MAIN_BLOCKS - 1) ? 1 : 0;
    }
    __syncthreads();

    if (flag && tid < 64) {                    // wave 0 of the last-finishing block
        float v = atomicAdd(&accum[tid * ACC_STRIDE], 0.0f);   // coherent read
#pragma unroll
        for (int off = 1; off <= 32; off <<= 1)
            v += __shfl_xor(v, off);
        if (tid == 0) out[0] = v * (1.0f / (float)NITEMS);
    }
}

extern "C" void kernel_launch(void* const* d_in, const int* in_sizes, int n_in,
                              void* d_out, int out_size, void* d_ws, size_t ws_size,
                              hipStream_t stream) {
    const float* pred   = (const float*)d_in[0];
    const float* target = (const float*)d_in[1];
    float* out = (float*)d_out;

    float4* packP = (float4*)d_ws;                              // 1 MB
    float4* packT = packP + (size_t)BATCH * NPTS;               // 1 MB
    float*  accum = (float*)(packT + (size_t)BATCH * NPTS);     // 64 slots x 64 B
    int*    counter = (int*)(accum + NACC * ACC_STRIDE);

    chamfer_prep<<<NITEMS / THREADS, THREADS, 0, stream>>>(
        pred, target, packP, packT, accum, counter);
    chamfer_main<<<MAIN_BLOCKS, THREADS, 0, stream>>>(
        packP, packT, accum, counter, out);
}